// Round 5
// baseline (237.945 us; speedup 1.0000x reference)
//
#include <hip/hip_runtime.h>

// Problem constants (from reference): B,N,H,W = 64,21,128,128
#define BB 64
#define NN 21
#define HH 128
#define WW 128
static constexpr long long TOT_ELEMS = (long long)BB * NN * HH * WW; // 22,020,096
static constexpr int NV4 = (int)(TOT_ELEMS / 4);                     // 5,505,024 float4s
static constexpr int NKP = BB * NN;                                  // 1344 keypoints

static constexpr int THREADS = 256;
static constexpr int BLOCKS  = 1792;              // 7 blocks/CU x 256 CUs
static constexpr int WPB     = 3;                 // windows per block
static_assert((long long)BLOCKS * WPB * 1024 == NV4, "exact tiling");

typedef float vfloat4 __attribute__((ext_vector_type(4)));

// NT loads: no cache allocation (harness poison-fill leaves L3 dirty; cached
// reads would trigger a poison writeback storm — prior-session verified).
__device__ __forceinline__ vfloat4 nt_load4(const vfloat4* p) {
    return __builtin_nontemporal_load(p);
}

// ============================================================================
// ROUND 5 = INSTRUMENTATION ROUND (strip the X-stream before final version).
//
// Purpose: combined_loss_partial has never been visible in the top-5 counter
// rows (cutoff ~51.5 us) -- we only know it is <51.5 us. The HBM floor for
// its 176 MB of reads is ~27 us. To decide "roofline vs 11% headroom" we
// need its real duration and achieved BW.
//
// Method: every block additionally reads the 3 windows belonging to block
// (bid + BLOCKS/2) % BLOCKS -- same addressing math, distinct addresses,
// +176 MB of DRAM traffic. The extra sums are kept alive with an empty
// asm volatile (prevents DCE, rule: ablation-via-skip DCEs upstream ops)
// but NEVER touch the output -> bit-identical result, absmax 0.0.
//   * kernel1 duration doubles -> crosses the top-5 cutoff -> we read its
//     hbm_gbps / FETCH_SIZE directly from rocprof.
//   * Delta(total dur) vs 176.0 us ~= kernel1's one-pass duration.
//
// __launch_bounds__(256, 7): 7 waves/EU min -> VGPR capped at 73 so the
// extra in-flight loads cannot drop residency below 7 blocks/CU (which
// would distort the measurement).
// ============================================================================
__global__ __launch_bounds__(THREADS, 7) void combined_loss_partial(
    const vfloat4* __restrict__ pred4,
    const vfloat4* __restrict__ gt4,
    const float*   __restrict__ pred,  // scalar view for the gather
    const float*   __restrict__ kp,    // (B,N,2) -> [x, y]
    float2* __restrict__ partial)      // partial[b] = {sum sq diff, sum (1-v)^2}
{
    const int t     = threadIdx.x;
    const int base  = blockIdx.x * (WPB * 1024) + t;
    // Instrumentation stream: the far block's windows (distinct DRAM lines).
    const int base2 = ((blockIdx.x + BLOCKS / 2) % BLOCKS) * (WPB * 1024) + t;

    float s0 = 0.0f, s1 = 0.0f, s2acc = 0.0f, s3 = 0.0f;
    float x0 = 0.0f, x1 = 0.0f, x2 = 0.0f, x3 = 0.0f;   // dead (kept alive)
    #pragma unroll
    for (int k = 0; k < WPB; ++k) {
        const int idx  = base  + k * 1024;
        const int idx2 = base2 + k * 1024;
        vfloat4 p0 = nt_load4(pred4 + idx);
        vfloat4 p1 = nt_load4(pred4 + idx + 256);
        vfloat4 p2 = nt_load4(pred4 + idx + 512);
        vfloat4 p3 = nt_load4(pred4 + idx + 768);
        vfloat4 g0 = nt_load4(gt4 + idx);
        vfloat4 g1 = nt_load4(gt4 + idx + 256);
        vfloat4 g2 = nt_load4(gt4 + idx + 512);
        vfloat4 g3 = nt_load4(gt4 + idx + 768);
        float d;
        d = p0.x - g0.x; s0 += d * d;    d = p0.y - g0.y; s0 += d * d;
        d = p0.z - g0.z; s0 += d * d;    d = p0.w - g0.w; s0 += d * d;
        d = p1.x - g1.x; s1 += d * d;    d = p1.y - g1.y; s1 += d * d;
        d = p1.z - g1.z; s1 += d * d;    d = p1.w - g1.w; s1 += d * d;
        d = p2.x - g2.x; s2acc += d * d; d = p2.y - g2.y; s2acc += d * d;
        d = p2.z - g2.z; s2acc += d * d; d = p2.w - g2.w; s2acc += d * d;
        d = p3.x - g3.x; s3 += d * d;    d = p3.y - g3.y; s3 += d * d;
        d = p3.z - g3.z; s3 += d * d;    d = p3.w - g3.w; s3 += d * d;

        // ---- instrumentation stream (same shape, different addresses) ----
        vfloat4 q0 = nt_load4(pred4 + idx2);
        vfloat4 q1 = nt_load4(pred4 + idx2 + 256);
        vfloat4 q2 = nt_load4(pred4 + idx2 + 512);
        vfloat4 q3 = nt_load4(pred4 + idx2 + 768);
        vfloat4 h0 = nt_load4(gt4 + idx2);
        vfloat4 h1 = nt_load4(gt4 + idx2 + 256);
        vfloat4 h2 = nt_load4(gt4 + idx2 + 512);
        vfloat4 h3 = nt_load4(gt4 + idx2 + 768);
        d = q0.x - h0.x; x0 += d * d;    d = q0.y - h0.y; x0 += d * d;
        d = q0.z - h0.z; x0 += d * d;    d = q0.w - h0.w; x0 += d * d;
        d = q1.x - h1.x; x1 += d * d;    d = q1.y - h1.y; x1 += d * d;
        d = q1.z - h1.z; x1 += d * d;    d = q1.w - h1.w; x1 += d * d;
        d = q2.x - h2.x; x2 += d * d;    d = q2.y - h2.y; x2 += d * d;
        d = q2.z - h2.z; x2 += d * d;    d = q2.w - h2.w; x2 += d * d;
        d = q3.x - h3.x; x3 += d * d;    d = q3.y - h3.y; x3 += d * d;
        d = q3.z - h3.z; x3 += d * d;    d = q3.w - h3.w; x3 += d * d;
    }
    float s = (s0 + s1) + (s2acc + s3);

    // Keep the instrumentation sums (and thus their loads) alive, then drop.
    float xsum = (x0 + x1) + (x2 + x3);
    asm volatile("" :: "v"(xsum));

    // Soft-PCK gather: gid == b*N + n, heatmap base offset = gid*H*W.
    const int gid = blockIdx.x * THREADS + t;
    float s2 = 0.0f;
    if (gid < NKP) {
        float px = kp[2 * gid + 0];
        float py = kp[2 * gid + 1];
        // jnp.clip(v, 0, dim-1).astype(int32): clamp then truncate toward zero
        int xi = (int)fminf(fmaxf(px, 0.0f), (float)(WW - 1));
        int yi = (int)fminf(fmaxf(py, 0.0f), (float)(HH - 1));
        float v = pred[(long long)gid * HH * WW + (long long)yi * WW + xi];
        float dd = 1.0f - v;
        s2 = dd * dd;
    }

    // Wave-64 reduce
    #pragma unroll
    for (int off = 32; off > 0; off >>= 1) {
        s  += __shfl_down(s,  off, 64);
        s2 += __shfl_down(s2, off, 64);
    }

    __shared__ float ls[4], ls2[4]; // 256 threads / 64 = 4 waves
    const int lane = t & 63;
    const int wid  = t >> 6;
    if (lane == 0) { ls[wid] = s; ls2[wid] = s2; }
    __syncthreads();
    if (t == 0) {
        float tt  = (ls[0] + ls[1]) + (ls[2] + ls[3]);
        float tt2 = (ls2[0] + ls2[1]) + (ls2[2] + ls2[3]);
        partial[blockIdx.x] = make_float2(tt, tt2);
    }
}

// Kernel 2: one block reduces the per-block partials and writes out.
// Cross-kernel visibility via stream ordering -- no fences, no atomics.
__global__ __launch_bounds__(THREADS) void combined_loss_final(
    const float2* __restrict__ partial,
    float* __restrict__ out)
{
    float s = 0.0f, s2 = 0.0f;
    for (int i = threadIdx.x; i < BLOCKS; i += THREADS) {
        float2 p = partial[i];
        s += p.x; s2 += p.y;
    }
    #pragma unroll
    for (int off = 32; off > 0; off >>= 1) {
        s  += __shfl_down(s,  off, 64);
        s2 += __shfl_down(s2, off, 64);
    }
    __shared__ float ls[4], ls2[4];
    const int lane = threadIdx.x & 63;
    const int wid  = threadIdx.x >> 6;
    if (lane == 0) { ls[wid] = s; ls2[wid] = s2; }
    __syncthreads();
    if (threadIdx.x == 0) {
        float t  = (ls[0] + ls[1]) + (ls[2] + ls[3]);
        float t2 = (ls2[0] + ls2[1]) + (ls2[2] + ls2[3]);
        float mse = t / (float)TOT_ELEMS;
        float pck = t2 / (float)NKP;
        out[0] = mse + pck; // MSE_WEIGHT = SOFT_PCK_WEIGHT = 1.0
        out[1] = mse;
        out[2] = pck;
    }
}

extern "C" void kernel_launch(void* const* d_in, const int* in_sizes, int n_in,
                              void* d_out, int out_size, void* d_ws, size_t ws_size,
                              hipStream_t stream) {
    const float* pred = (const float*)d_in[0]; // (B,N,H,W)
    const float* gt   = (const float*)d_in[1]; // (B,N,H,W)
    const float* kp   = (const float*)d_in[2]; // (B,N,2)
    float* out = (float*)d_out;
    float2* partial = (float2*)d_ws;           // BLOCKS float2s = 14 KB

    combined_loss_partial<<<BLOCKS, THREADS, 0, stream>>>(
        (const vfloat4*)pred, (const vfloat4*)gt, pred, kp, partial);

    combined_loss_final<<<1, THREADS, 0, stream>>>(partial, out);
}

// Round 6
// 176.977 us; speedup vs baseline: 1.3445x; 1.3445x over previous
//
#include <hip/hip_runtime.h>

// Problem constants (from reference): B,N,H,W = 64,21,128,128
#define BB 64
#define NN 21
#define HH 128
#define WW 128
static constexpr long long TOT_ELEMS = (long long)BB * NN * HH * WW; // 22,020,096
static constexpr int NV4 = (int)(TOT_ELEMS / 4);                     // 5,505,024 float4s
static constexpr int NKP = BB * NN;                                  // 1344 keypoints

// 5,505,024 float4 = 5376 windows of 1024 float4 (16 KB).
// 1792 blocks x 3 windows x 1024 == NV4 exactly -> no tail code.
static constexpr int THREADS = 256;
static constexpr int BLOCKS  = 1792;              // 7 blocks/CU x 256 CUs
static constexpr int WPB     = 3;                 // windows per block
static_assert((long long)BLOCKS * WPB * 1024 == NV4, "exact tiling");

// Native clang vector type: __builtin_nontemporal_load requires a pointer to
// scalar/vector-of-scalar, not HIP's float4 struct.
typedef float vfloat4 __attribute__((ext_vector_type(4)));

// Non-temporal load (global_load_dwordx4 ... nt): no cache allocation.
// The harness re-poisons a 336 MB d_ws before every timed launch, leaving L3
// full of dirty poison lines. Cached reads would allocate -> evict poison ->
// writeback storm (prior session: 66 MB WRITE_SIZE, 2.3 TB/s). NT reads
// leave L3 alone.
//
// ============================ SESSION JOURNAL ==============================
//  R0: two-kernel baseline, 175.8 us, absmax 0.0 (GREEN anchor).
//  R1: fused 1-kernel w/ __threadfence -> buffer_wbl2 per block = full L2
//      writeback walk x1792 -> kernel 122 us, traffic-INVARIANT (cache-warm
//      replay also 122 us). REGRESSION, reverted.
//  R2/R3: fence-free fusion (__hip_atomic AGENT sc1): container failed
//      twice; upside was only ~5 us -> fusion permanently abandoned.
//  R4: reverted to R0 structure -> 176.0 us GREEN. Kernel1 still invisible
//      (< top-5 cutoff 51.5 us); roofline unresolved.
//  R5: INSTRUMENTATION -- added a dead-but-live 2nd read stream (+176 MB):
//      doubled kernel = 94.1 us, total 237.9 us.
//      => one-pass kernel1 = 94.1 - (237.9-176.0) = ~32 us.
//      => ideal read floor 176 MB @ 6.7-6.8 TB/s = 26-28 us, PLUS measured
//         88 MB of harness-poison L2/L3->HBM write drain DURING our window
//         (WRITE_SIZE=87.8 MB vs 14 KB actually written by the kernel)
//         sharing the bus -> realistic floor ~30-34 us. Kernel1 IS at the
//         memory roofline. VALUBusy 3.7%, conflicts 0, occupancy 56%.
//      Total 176 us = kernel1 ~32 + kernel2 ~3 + ~140 us harness poison
//      fills/memsets/graph gaps (outside kernel_launch control).
//      Remaining controllable headroom < 2% -> declare roofline.
// ===========================================================================
__device__ __forceinline__ vfloat4 nt_load4(const vfloat4* p) {
    return __builtin_nontemporal_load(p);
}

// Kernel 1: block-contiguous MSE accumulation. Each block reads 3 contiguous
// 16 KB windows per stream; a wave's 8 in-flight loads are 4 KB apart (DRAM
// page-friendly). First NKP global threads also do the keypoint gather.
__global__ __launch_bounds__(THREADS) void combined_loss_partial(
    const vfloat4* __restrict__ pred4,
    const vfloat4* __restrict__ gt4,
    const float*   __restrict__ pred,  // scalar view for the gather
    const float*   __restrict__ kp,    // (B,N,2) -> [x, y]
    float2* __restrict__ partial)      // partial[b] = {sum sq diff, sum (1-v)^2}
{
    const int t    = threadIdx.x;
    const int base = blockIdx.x * (WPB * 1024) + t;

    float s0 = 0.0f, s1 = 0.0f, s2acc = 0.0f, s3 = 0.0f;
    #pragma unroll
    for (int k = 0; k < WPB; ++k) {
        const int idx = base + k * 1024;
        vfloat4 p0 = nt_load4(pred4 + idx);
        vfloat4 p1 = nt_load4(pred4 + idx + 256);
        vfloat4 p2 = nt_load4(pred4 + idx + 512);
        vfloat4 p3 = nt_load4(pred4 + idx + 768);
        vfloat4 g0 = nt_load4(gt4 + idx);
        vfloat4 g1 = nt_load4(gt4 + idx + 256);
        vfloat4 g2 = nt_load4(gt4 + idx + 512);
        vfloat4 g3 = nt_load4(gt4 + idx + 768);
        float d;
        d = p0.x - g0.x; s0 += d * d;    d = p0.y - g0.y; s0 += d * d;
        d = p0.z - g0.z; s0 += d * d;    d = p0.w - g0.w; s0 += d * d;
        d = p1.x - g1.x; s1 += d * d;    d = p1.y - g1.y; s1 += d * d;
        d = p1.z - g1.z; s1 += d * d;    d = p1.w - g1.w; s1 += d * d;
        d = p2.x - g2.x; s2acc += d * d; d = p2.y - g2.y; s2acc += d * d;
        d = p2.z - g2.z; s2acc += d * d; d = p2.w - g2.w; s2acc += d * d;
        d = p3.x - g3.x; s3 += d * d;    d = p3.y - g3.y; s3 += d * d;
        d = p3.z - g3.z; s3 += d * d;    d = p3.w - g3.w; s3 += d * d;
    }
    float s = (s0 + s1) + (s2acc + s3);

    // Soft-PCK gather: gid == b*N + n, heatmap base offset = gid*H*W.
    const int gid = blockIdx.x * THREADS + t;
    float s2 = 0.0f;
    if (gid < NKP) {
        float px = kp[2 * gid + 0];
        float py = kp[2 * gid + 1];
        // jnp.clip(v, 0, dim-1).astype(int32): clamp then truncate toward zero
        int xi = (int)fminf(fmaxf(px, 0.0f), (float)(WW - 1));
        int yi = (int)fminf(fmaxf(py, 0.0f), (float)(HH - 1));
        float v = pred[(long long)gid * HH * WW + (long long)yi * WW + xi];
        float dd = 1.0f - v;
        s2 = dd * dd;
    }

    // Wave-64 reduce
    #pragma unroll
    for (int off = 32; off > 0; off >>= 1) {
        s  += __shfl_down(s,  off, 64);
        s2 += __shfl_down(s2, off, 64);
    }

    __shared__ float ls[4], ls2[4]; // 256 threads / 64 = 4 waves
    const int lane = t & 63;
    const int wid  = t >> 6;
    if (lane == 0) { ls[wid] = s; ls2[wid] = s2; }
    __syncthreads();
    if (t == 0) {
        float tt  = (ls[0] + ls[1]) + (ls[2] + ls[3]);
        float tt2 = (ls2[0] + ls2[1]) + (ls2[2] + ls2[3]);
        partial[blockIdx.x] = make_float2(tt, tt2);
    }
}

// Kernel 2: one block reduces the per-block partials and writes out.
// Cross-kernel visibility via stream ordering (kernel-boundary cache flush)
// -- no fences, no atomics, no sc1 ops.
__global__ __launch_bounds__(THREADS) void combined_loss_final(
    const float2* __restrict__ partial,
    float* __restrict__ out)
{
    float s = 0.0f, s2 = 0.0f;
    for (int i = threadIdx.x; i < BLOCKS; i += THREADS) {
        float2 p = partial[i];
        s += p.x; s2 += p.y;
    }
    #pragma unroll
    for (int off = 32; off > 0; off >>= 1) {
        s  += __shfl_down(s,  off, 64);
        s2 += __shfl_down(s2, off, 64);
    }
    __shared__ float ls[4], ls2[4];
    const int lane = threadIdx.x & 63;
    const int wid  = threadIdx.x >> 6;
    if (lane == 0) { ls[wid] = s; ls2[wid] = s2; }
    __syncthreads();
    if (threadIdx.x == 0) {
        float t  = (ls[0] + ls[1]) + (ls[2] + ls[3]);
        float t2 = (ls2[0] + ls2[1]) + (ls2[2] + ls2[3]);
        float mse = t / (float)TOT_ELEMS;
        float pck = t2 / (float)NKP;
        out[0] = mse + pck; // MSE_WEIGHT = SOFT_PCK_WEIGHT = 1.0
        out[1] = mse;
        out[2] = pck;
    }
}

extern "C" void kernel_launch(void* const* d_in, const int* in_sizes, int n_in,
                              void* d_out, int out_size, void* d_ws, size_t ws_size,
                              hipStream_t stream) {
    const float* pred = (const float*)d_in[0]; // (B,N,H,W)
    const float* gt   = (const float*)d_in[1]; // (B,N,H,W)
    const float* kp   = (const float*)d_in[2]; // (B,N,2)
    float* out = (float*)d_out;
    float2* partial = (float2*)d_ws;           // BLOCKS float2s = 14 KB

    combined_loss_partial<<<BLOCKS, THREADS, 0, stream>>>(
        (const vfloat4*)pred, (const vfloat4*)gt, pred, kp, partial);

    combined_loss_final<<<1, THREADS, 0, stream>>>(partial, out);
}